// Round 3
// baseline (649.003 us; speedup 1.0000x reference)
//
#include <hip/hip_runtime.h>

// Problem constants (from reference): memory [E, M, D] fp32
constexpr int E = 1024;
constexpr int M = 200;
constexpr int D = 512;
constexpr long long TOT = (long long)E * M * D;   // 104,857,600 floats
constexpr int PER_ENV4 = M * D / 4;               // 25,600 float4 per env
constexpr int PER_ROW4 = D / 4;                   // 128 float4 per row
constexpr int BLOCK = 256;
constexpr int CHUNKS = PER_ENV4 / BLOCK;          // 100 blocks per env
constexpr float NOVELTY_THRESHOLD = 0.5f;

// Native clang vector type: __builtin_nontemporal_* requires scalar or
// native-vector pointee (HIP_vector_type float4 is rejected).
typedef float f32x4 __attribute__((ext_vector_type(4)));

// Grid: (CHUNKS, E). blockIdx.y == env, so all per-env metadata addresses are
// wave-uniform -> compiler emits scalar s_load for sim/mask/ridx (no per-lane
// vector loads, no integer magic-mul division on the hot path).
__global__ __launch_bounds__(BLOCK) void reach_update(
    const f32x4* __restrict__ mem,      // [E*M*D/4]
    const f32x4* __restrict__ obs,      // [E*D/4]
    const float* __restrict__ sim,      // [E]
    const int*   __restrict__ mask,     // [E]
    const int*   __restrict__ ridx,     // [E]
    f32x4*       __restrict__ out_mem,  // [E*M*D/4]
    float*       __restrict__ out_mask  // [E], written as float (exact <= 201)
) {
    const int e = blockIdx.y;
    const int t = blockIdx.x * BLOCK + threadIdx.x;   // [0, 25600) within env
    const int i4 = e * PER_ENV4 + t;                  // < 2^25, int is safe

    // Per-env metadata (uniform): which row, if any, gets replaced.
    const float s    = sim[e];
    const int   mk   = mask[e];
    const bool  add  = s > NOVELTY_THRESHOLD;
    const bool  full = (mk == M);
    const int   nm   = mk + ((!full) && add ? 1 : 0);
    int am1 = nm - 1; if (am1 < 0) am1 = 0;
    const int   idx  = full ? ridx[e] : am1;

    const int row  = t >> 7;              // / PER_ROW4 (128)
    const int col4 = t & (PER_ROW4 - 1);

    // Pure 16B/lane stream; nt: no reuse exists (re-poisoned every iter,
    // 419 MB > 256 MB L3), so skip cache pollution.
    f32x4 v = __builtin_nontemporal_load(&mem[i4]);
    if (add && row == idx) {
        v = obs[e * PER_ROW4 + col4];
    }
    __builtin_nontemporal_store(v, &out_mem[i4]);

    // One lane per env emits the updated counter.
    if (blockIdx.x == 0 && threadIdx.x == 0) {
        out_mask[e] = (float)nm;
    }
}

extern "C" void kernel_launch(void* const* d_in, const int* in_sizes, int n_in,
                              void* d_out, int out_size, void* d_ws, size_t ws_size,
                              hipStream_t stream) {
    const f32x4* mem  = (const f32x4*)d_in[0];
    const f32x4* obs  = (const f32x4*)d_in[1];
    const float* sim  = (const float*)d_in[2];
    const int*   mask = (const int*)d_in[3];
    const int*   ridx = (const int*)d_in[4];

    float* out      = (float*)d_out;
    float* out_mask = out + TOT;   // mask tail starts after the memory bank

    dim3 grid(CHUNKS, E);          // (100, 1024) = 102,400 blocks
    reach_update<<<grid, dim3(BLOCK), 0, stream>>>(mem, obs, sim, mask, ridx,
                                                   (f32x4*)out, out_mask);
}